// Round 1
// baseline (1442.613 us; speedup 1.0000x reference)
//
#include <hip/hip_runtime.h>

#define N_NODES 100000
#define N_EDGES 3200000

// ---------------- zero kernel ----------------
__global__ __launch_bounds__(256) void zero_f4_kernel(float4* __restrict__ p, int n4) {
    int i = blockIdx.x * blockDim.x + threadIdx.x;
    int stride = gridDim.x * blockDim.x;
    for (; i < n4; i += stride) p[i] = make_float4(0.f, 0.f, 0.f, 0.f);
}

// ---------------- GEMM1: H1[M,64] = X[M,512] @ W1[512,64] ----------------
#define BM 128
#define BN 64
#define BK 16
// 128 threads, thread grid 16 (M-groups of 8) x 8 (N-groups of 8)
__global__ __launch_bounds__(128) void gemm1_kernel(const float* __restrict__ X,
                                                    const float* __restrict__ W1,
                                                    float* __restrict__ H1) {
    __shared__ float As[BK][BM];   // [k][m]
    __shared__ float Bs[BK][BN];   // [k][n]

    const int tid = threadIdx.x;
    const int mg = tid >> 3;   // 0..15
    const int ng = tid & 7;    // 0..7
    const long row0 = (long)blockIdx.x * BM;

    float4 pa[4];
    float4 pb[2];

    auto loadA = [&](int k0) {
        #pragma unroll
        for (int f = 0; f < 4; ++f) {
            int q = tid + f * 128;          // 0..511
            int r = q >> 2;                 // 0..127
            int k4 = (q & 3) << 2;          // 0,4,8,12
            long grow = row0 + r;
            if (grow < N_NODES)
                pa[f] = *reinterpret_cast<const float4*>(X + grow * 512 + k0 + k4);
            else
                pa[f] = make_float4(0.f, 0.f, 0.f, 0.f);
        }
    };
    auto loadB = [&](int k0) {
        #pragma unroll
        for (int f = 0; f < 2; ++f) {
            int q = tid + f * 128;          // 0..255
            int kk = q >> 4;                // 0..15
            int j4 = (q & 15) << 2;         // 0..60
            pb[f] = *reinterpret_cast<const float4*>(W1 + (long)(k0 + kk) * 64 + j4);
        }
    };
    auto storeA = [&]() {
        #pragma unroll
        for (int f = 0; f < 4; ++f) {
            int q = tid + f * 128;
            int r = q >> 2;
            int k4 = (q & 3) << 2;
            As[k4 + 0][r] = pa[f].x;
            As[k4 + 1][r] = pa[f].y;
            As[k4 + 2][r] = pa[f].z;
            As[k4 + 3][r] = pa[f].w;
        }
    };
    auto storeB = [&]() {
        #pragma unroll
        for (int f = 0; f < 2; ++f) {
            int q = tid + f * 128;
            int kk = q >> 4;
            int j4 = (q & 15) << 2;
            *reinterpret_cast<float4*>(&Bs[kk][j4]) = pb[f];
        }
    };

    float acc[8][8];
    #pragma unroll
    for (int m = 0; m < 8; ++m)
        #pragma unroll
        for (int n = 0; n < 8; ++n) acc[m][n] = 0.f;

    loadA(0);
    loadB(0);
    storeA();
    storeB();
    __syncthreads();

    for (int k0 = 0; k0 < 512; k0 += BK) {
        const bool has_next = (k0 + BK) < 512;
        if (has_next) { loadA(k0 + BK); loadB(k0 + BK); }

        #pragma unroll
        for (int kk = 0; kk < BK; ++kk) {
            float a[8], b[8];
            *reinterpret_cast<float4*>(&a[0]) = *reinterpret_cast<const float4*>(&As[kk][mg * 8]);
            *reinterpret_cast<float4*>(&a[4]) = *reinterpret_cast<const float4*>(&As[kk][mg * 8 + 4]);
            *reinterpret_cast<float4*>(&b[0]) = *reinterpret_cast<const float4*>(&Bs[kk][ng * 8]);
            *reinterpret_cast<float4*>(&b[4]) = *reinterpret_cast<const float4*>(&Bs[kk][ng * 8 + 4]);
            #pragma unroll
            for (int m = 0; m < 8; ++m)
                #pragma unroll
                for (int n = 0; n < 8; ++n) acc[m][n] += a[m] * b[n];
        }
        __syncthreads();
        if (has_next) {
            storeA();
            storeB();
            __syncthreads();
        }
    }

    #pragma unroll
    for (int m = 0; m < 8; ++m) {
        long grow = row0 + mg * 8 + m;
        if (grow < N_NODES) {
            #pragma unroll
            for (int n = 0; n < 8; n += 4) {
                *reinterpret_cast<float4*>(H1 + grow * 64 + ng * 8 + n) =
                    make_float4(acc[m][n], acc[m][n + 1], acc[m][n + 2], acc[m][n + 3]);
            }
        }
    }
}

// ---------------- SPMM1: H2[r] += val[e] * H1[col[e]], D=64 ----------------
// one wave per edge, lane = feature
__global__ __launch_bounds__(256) void spmm1_kernel(const int* __restrict__ row,
                                                    const int* __restrict__ col,
                                                    const float* __restrict__ val,
                                                    const float* __restrict__ H1,
                                                    float* __restrict__ H2) {
    int e = blockIdx.x * 4 + (threadIdx.x >> 6);
    int lane = threadIdx.x & 63;
    if (e >= N_EDGES) return;
    int r = row[e];
    int c = col[e];
    float v = val[e];
    atomicAdd(H2 + (long)r * 64 + lane, v * H1[(long)c * 64 + lane]);
}

// ---------------- GEMM2 fused relu: H3[M,40] = relu(H2[M,64]) @ W2[64,40] ----------------
// 320 threads, 8 rows/block, one output element per thread
__global__ __launch_bounds__(320) void gemm2_relu_kernel(const float* __restrict__ H2,
                                                         const float* __restrict__ W2,
                                                         float* __restrict__ H3) {
    __shared__ float hs[8 * 64];
    __shared__ float ws[64 * 40];
    const int r0 = blockIdx.x * 8;

    for (int i = threadIdx.x; i < 8 * 64; i += 320) {
        int r = r0 + (i >> 6);
        float v = (r < N_NODES) ? H2[(long)r * 64 + (i & 63)] : 0.f;
        hs[i] = v > 0.f ? v : 0.f;
    }
    for (int i = threadIdx.x; i < 64 * 40; i += 320) ws[i] = W2[i];
    __syncthreads();

    const int rl = threadIdx.x / 40;
    const int d = threadIdx.x % 40;
    float acc = 0.f;
    #pragma unroll
    for (int k = 0; k < 64; ++k) acc += hs[rl * 64 + k] * ws[k * 40 + d];

    const int r = r0 + rl;
    if (r < N_NODES) H3[(long)r * 40 + d] = acc;
}

// ---------------- SPMM2: OUT[r] += val[e] * H3[col[e]], D=40 ----------------
// 320 threads = 8 edges x 40 feats per block
__global__ __launch_bounds__(320) void spmm2_kernel(const int* __restrict__ row,
                                                    const int* __restrict__ col,
                                                    const float* __restrict__ val,
                                                    const float* __restrict__ H3,
                                                    float* __restrict__ OUT) {
    int e = blockIdx.x * 8 + threadIdx.x / 40;
    int d = threadIdx.x % 40;
    if (e >= N_EDGES) return;
    int r = row[e];
    int c = col[e];
    float v = val[e];
    atomicAdd(OUT + (long)r * 40 + d, v * H3[(long)c * 40 + d]);
}

extern "C" void kernel_launch(void* const* d_in, const int* in_sizes, int n_in,
                              void* d_out, int out_size, void* d_ws, size_t ws_size,
                              hipStream_t stream) {
    const float* x       = (const float*)d_in[0];
    const float* W1      = (const float*)d_in[1];
    const float* W2      = (const float*)d_in[2];
    const float* adj_val = (const float*)d_in[3];
    const int*   adj_row = (const int*)d_in[4];
    const int*   adj_col = (const int*)d_in[5];
    float* out = (float*)d_out;

    // workspace layout
    char* ws = (char*)d_ws;
    float* h1 = (float*)(ws);                         // 100000*64*4 = 25.6 MB
    float* h2 = (float*)(ws + 25600000);              // 25.6 MB
    float* h3 = (float*)(ws);                         // 16 MB, reuses h1 (dead after spmm1)

    // 1. zero h2 (spmm1 accumulator)
    zero_f4_kernel<<<2048, 256, 0, stream>>>((float4*)h2, N_NODES * 64 / 4);

    // 2. gemm1: h1 = x @ W1
    gemm1_kernel<<<(N_NODES + BM - 1) / BM, 128, 0, stream>>>(x, W1, h1);

    // 3. spmm1: h2 = A @ h1
    spmm1_kernel<<<N_EDGES / 4, 256, 0, stream>>>(adj_row, adj_col, adj_val, h1, h2);

    // 4. gemm2+relu: h3 = relu(h2) @ W2
    gemm2_relu_kernel<<<(N_NODES + 7) / 8, 320, 0, stream>>>(h2, W2, h3);

    // 5. zero out (spmm2 accumulator)
    zero_f4_kernel<<<2048, 256, 0, stream>>>((float4*)out, N_NODES * 40 / 4);

    // 6. spmm2: out = A @ h3
    spmm2_kernel<<<N_EDGES / 8, 320, 0, stream>>>(adj_row, adj_col, adj_val, h3, out);
}

// Round 2
// 930.759 us; speedup vs baseline: 1.5499x; 1.5499x over previous
//
#include <hip/hip_runtime.h>

#define N_NODES 100000
#define N_EDGES 3200000
#define SCAN_NB 391   // ceil(N_NODES/256)

// ---------------- zero kernels ----------------
__global__ __launch_bounds__(256) void zero_f4_kernel(float4* __restrict__ p, int n4) {
    int i = blockIdx.x * blockDim.x + threadIdx.x;
    int stride = gridDim.x * blockDim.x;
    for (; i < n4; i += stride) p[i] = make_float4(0.f, 0.f, 0.f, 0.f);
}

__global__ __launch_bounds__(256) void zero_int_kernel(int* __restrict__ p, int n) {
    int i = blockIdx.x * 256 + threadIdx.x;
    if (i < n) p[i] = 0;
}

// ---------------- CSR build ----------------
__global__ __launch_bounds__(256) void hist_kernel(const int* __restrict__ row,
                                                   int* __restrict__ deg) {
    int e = blockIdx.x * 256 + threadIdx.x;
    if (e < N_EDGES) atomicAdd(&deg[row[e]], 1);
}

__global__ __launch_bounds__(256) void scan_a_kernel(const int* __restrict__ deg,
                                                     int* __restrict__ rowptr,
                                                     int* __restrict__ partials) {
    __shared__ int sm[256];
    const int tid = threadIdx.x;
    const int i = blockIdx.x * 256 + tid;
    int v = (i < N_NODES) ? deg[i] : 0;
    sm[tid] = v;
    __syncthreads();
    #pragma unroll
    for (int off = 1; off < 256; off <<= 1) {
        int t = (tid >= off) ? sm[tid - off] : 0;
        __syncthreads();
        sm[tid] += t;
        __syncthreads();
    }
    if (i < N_NODES) rowptr[i] = sm[tid] - v;   // block-local exclusive
    if (tid == 255) partials[blockIdx.x] = sm[255];
}

__global__ __launch_bounds__(512) void scan_b_kernel(int* __restrict__ partials,
                                                     int* __restrict__ rowptr) {
    __shared__ int sm[512];
    const int tid = threadIdx.x;
    int v = (tid < SCAN_NB) ? partials[tid] : 0;
    sm[tid] = v;
    __syncthreads();
    #pragma unroll
    for (int off = 1; off < 512; off <<= 1) {
        int t = (tid >= off) ? sm[tid - off] : 0;
        __syncthreads();
        sm[tid] += t;
        __syncthreads();
    }
    if (tid < SCAN_NB) partials[tid] = sm[tid] - v;  // exclusive block bases
    if (tid == 511) rowptr[N_NODES] = sm[511];       // grand total (= N_EDGES)
}

__global__ __launch_bounds__(256) void scan_c_kernel(int* __restrict__ rowptr,
                                                     int* __restrict__ cursor,
                                                     const int* __restrict__ partials) {
    int i = blockIdx.x * 256 + threadIdx.x;
    if (i < N_NODES) {
        int v = rowptr[i] + partials[blockIdx.x];
        rowptr[i] = v;
        cursor[i] = v;
    }
}

__global__ __launch_bounds__(256) void scatter_kernel(const int* __restrict__ row,
                                                      const int* __restrict__ col,
                                                      const float* __restrict__ val,
                                                      int* __restrict__ cursor,
                                                      int2* __restrict__ edges) {
    int e = blockIdx.x * 256 + threadIdx.x;
    if (e >= N_EDGES) return;
    int r = row[e];
    int idx = atomicAdd(&cursor[r], 1);
    edges[idx] = make_int2(col[e], __float_as_int(val[e]));
}

// ---------------- CSR pull-mode SPMM: one wave per row ----------------
template<int D, bool RELU>
__global__ __launch_bounds__(256) void spmm_csr_kernel(const int* __restrict__ rowptr,
                                                       const int2* __restrict__ edges,
                                                       const float* __restrict__ H,
                                                       float* __restrict__ O) {
    const int r = blockIdx.x * 4 + (threadIdx.x >> 6);
    if (r >= N_NODES) return;
    const int lane = threadIdx.x & 63;
    const int start = rowptr[r];
    const int end = rowptr[r + 1];
    float acc = 0.f;
    for (int base = start; base < end; base += 64) {
        const int n = end - base;
        int c = 0;
        float v = 0.f;
        if (lane < n) {
            int2 ev = edges[base + lane];
            c = ev.x;
            v = __int_as_float(ev.y);
        }
        const int cnt = n < 64 ? n : 64;
        for (int j = 0; j < cnt; ++j) {
            int cj = __shfl(c, j);
            float vj = __shfl(v, j);
            if (lane < D) acc += vj * H[(long)cj * D + lane];
        }
    }
    if (RELU) acc = acc > 0.f ? acc : 0.f;
    if (lane < D) O[(long)r * D + lane] = acc;
}

// ---------------- GEMM1: H1[M,64] = X[M,512] @ W1[512,64] ----------------
#define BM 128
#define BN 64
#define BK 16
__global__ __launch_bounds__(128) void gemm1_kernel(const float* __restrict__ X,
                                                    const float* __restrict__ W1,
                                                    float* __restrict__ H1) {
    __shared__ float As[BK][BM];
    __shared__ float Bs[BK][BN];

    const int tid = threadIdx.x;
    const int mg = tid >> 3;
    const int ng = tid & 7;
    const long row0 = (long)blockIdx.x * BM;

    float4 pa[4];
    float4 pb[2];

    auto loadA = [&](int k0) {
        #pragma unroll
        for (int f = 0; f < 4; ++f) {
            int q = tid + f * 128;
            int r = q >> 2;
            int k4 = (q & 3) << 2;
            long grow = row0 + r;
            if (grow < N_NODES)
                pa[f] = *reinterpret_cast<const float4*>(X + grow * 512 + k0 + k4);
            else
                pa[f] = make_float4(0.f, 0.f, 0.f, 0.f);
        }
    };
    auto loadB = [&](int k0) {
        #pragma unroll
        for (int f = 0; f < 2; ++f) {
            int q = tid + f * 128;
            int kk = q >> 4;
            int j4 = (q & 15) << 2;
            pb[f] = *reinterpret_cast<const float4*>(W1 + (long)(k0 + kk) * 64 + j4);
        }
    };
    auto storeA = [&]() {
        #pragma unroll
        for (int f = 0; f < 4; ++f) {
            int q = tid + f * 128;
            int r = q >> 2;
            int k4 = (q & 3) << 2;
            As[k4 + 0][r] = pa[f].x;
            As[k4 + 1][r] = pa[f].y;
            As[k4 + 2][r] = pa[f].z;
            As[k4 + 3][r] = pa[f].w;
        }
    };
    auto storeB = [&]() {
        #pragma unroll
        for (int f = 0; f < 2; ++f) {
            int q = tid + f * 128;
            int kk = q >> 4;
            int j4 = (q & 15) << 2;
            *reinterpret_cast<float4*>(&Bs[kk][j4]) = pb[f];
        }
    };

    float acc[8][8];
    #pragma unroll
    for (int m = 0; m < 8; ++m)
        #pragma unroll
        for (int n = 0; n < 8; ++n) acc[m][n] = 0.f;

    loadA(0);
    loadB(0);
    storeA();
    storeB();
    __syncthreads();

    for (int k0 = 0; k0 < 512; k0 += BK) {
        const bool has_next = (k0 + BK) < 512;
        if (has_next) { loadA(k0 + BK); loadB(k0 + BK); }

        #pragma unroll
        for (int kk = 0; kk < BK; ++kk) {
            float a[8], b[8];
            *reinterpret_cast<float4*>(&a[0]) = *reinterpret_cast<const float4*>(&As[kk][mg * 8]);
            *reinterpret_cast<float4*>(&a[4]) = *reinterpret_cast<const float4*>(&As[kk][mg * 8 + 4]);
            *reinterpret_cast<float4*>(&b[0]) = *reinterpret_cast<const float4*>(&Bs[kk][ng * 8]);
            *reinterpret_cast<float4*>(&b[4]) = *reinterpret_cast<const float4*>(&Bs[kk][ng * 8 + 4]);
            #pragma unroll
            for (int m = 0; m < 8; ++m)
                #pragma unroll
                for (int n = 0; n < 8; ++n) acc[m][n] += a[m] * b[n];
        }
        __syncthreads();
        if (has_next) {
            storeA();
            storeB();
            __syncthreads();
        }
    }

    #pragma unroll
    for (int m = 0; m < 8; ++m) {
        long grow = row0 + mg * 8 + m;
        if (grow < N_NODES) {
            #pragma unroll
            for (int n = 0; n < 8; n += 4) {
                *reinterpret_cast<float4*>(H1 + grow * 64 + ng * 8 + n) =
                    make_float4(acc[m][n], acc[m][n + 1], acc[m][n + 2], acc[m][n + 3]);
            }
        }
    }
}

// ---------------- GEMM2: H3[M,40] = (optionally relu)(H2[M,64]) @ W2[64,40] ----------------
template<bool RELU_IN>
__global__ __launch_bounds__(320) void gemm2_kernel(const float* __restrict__ H2,
                                                    const float* __restrict__ W2,
                                                    float* __restrict__ H3) {
    __shared__ float hs[8 * 64];
    __shared__ float ws[64 * 40];
    const int r0 = blockIdx.x * 8;

    for (int i = threadIdx.x; i < 8 * 64; i += 320) {
        int r = r0 + (i >> 6);
        float v = (r < N_NODES) ? H2[(long)r * 64 + (i & 63)] : 0.f;
        if (RELU_IN) v = v > 0.f ? v : 0.f;
        hs[i] = v;
    }
    for (int i = threadIdx.x; i < 64 * 40; i += 320) ws[i] = W2[i];
    __syncthreads();

    const int rl = threadIdx.x / 40;
    const int d = threadIdx.x % 40;
    float acc = 0.f;
    #pragma unroll
    for (int k = 0; k < 64; ++k) acc += hs[rl * 64 + k] * ws[k * 40 + d];

    const int r = r0 + rl;
    if (r < N_NODES) H3[(long)r * 40 + d] = acc;
}

// ---------------- fallback atomic SPMMs (used only if ws too small) ----------------
__global__ __launch_bounds__(256) void spmm1_atomic_kernel(const int* __restrict__ row,
                                                           const int* __restrict__ col,
                                                           const float* __restrict__ val,
                                                           const float* __restrict__ H1,
                                                           float* __restrict__ H2) {
    int e = blockIdx.x * 4 + (threadIdx.x >> 6);
    int lane = threadIdx.x & 63;
    if (e >= N_EDGES) return;
    atomicAdd(H2 + (long)row[e] * 64 + lane, val[e] * H1[(long)col[e] * 64 + lane]);
}

__global__ __launch_bounds__(320) void spmm2_atomic_kernel(const int* __restrict__ row,
                                                           const int* __restrict__ col,
                                                           const float* __restrict__ val,
                                                           const float* __restrict__ H3,
                                                           float* __restrict__ OUT) {
    int e = blockIdx.x * 8 + threadIdx.x / 40;
    int d = threadIdx.x % 40;
    if (e >= N_EDGES) return;
    atomicAdd(OUT + (long)row[e] * 40 + d, val[e] * H3[(long)col[e] * 40 + d]);
}

extern "C" void kernel_launch(void* const* d_in, const int* in_sizes, int n_in,
                              void* d_out, int out_size, void* d_ws, size_t ws_size,
                              hipStream_t stream) {
    const float* x       = (const float*)d_in[0];
    const float* W1      = (const float*)d_in[1];
    const float* W2      = (const float*)d_in[2];
    const float* adj_val = (const float*)d_in[3];
    const int*   adj_row = (const int*)d_in[4];
    const int*   adj_col = (const int*)d_in[5];
    float* out = (float*)d_out;

    char* ws = (char*)d_ws;
    // layout
    const size_t OFF_H1     = 0;                       // 25.6 MB (h3 reuses this after spmm1)
    const size_t OFF_H2     = 25600000;                // 25.6 MB
    const size_t OFF_EDGES  = 51200000;                // 25.6 MB (int2 col+val, CSR order)
    const size_t OFF_ROWPTR = 76800000;                // 400,004 B
    const size_t OFF_CURSOR = 77200016;                // 400,000 B
    const size_t OFF_DEG    = 77600016;                // 400,000 B
    const size_t OFF_PART   = 78000016;                // 2,048 B
    const size_t WS_NEED    = 78002064;

    float* h1     = (float*)(ws + OFF_H1);
    float* h2     = (float*)(ws + OFF_H2);
    float* h3     = (float*)(ws + OFF_H1);  // overlays h1 (dead after spmm1)
    int2*  edges  = (int2*)(ws + OFF_EDGES);
    int*   rowptr = (int*)(ws + OFF_ROWPTR);
    int*   cursor = (int*)(ws + OFF_CURSOR);
    int*   deg    = (int*)(ws + OFF_DEG);
    int*   part   = (int*)(ws + OFF_PART);

    if (ws_size >= WS_NEED) {
        // ---- CSR build (independent of gemm1) ----
        zero_int_kernel<<<SCAN_NB, 256, 0, stream>>>(deg, N_NODES);
        hist_kernel<<<N_EDGES / 256, 256, 0, stream>>>(adj_row, deg);
        scan_a_kernel<<<SCAN_NB, 256, 0, stream>>>(deg, rowptr, part);
        scan_b_kernel<<<1, 512, 0, stream>>>(part, rowptr);
        scan_c_kernel<<<SCAN_NB, 256, 0, stream>>>(rowptr, cursor, part);
        scatter_kernel<<<N_EDGES / 256, 256, 0, stream>>>(adj_row, adj_col, adj_val, cursor, edges);

        // ---- dense + sparse pipeline ----
        gemm1_kernel<<<(N_NODES + BM - 1) / BM, 128, 0, stream>>>(x, W1, h1);
        spmm_csr_kernel<64, true><<<(N_NODES + 3) / 4, 256, 0, stream>>>(rowptr, edges, h1, h2);
        gemm2_kernel<false><<<(N_NODES + 7) / 8, 320, 0, stream>>>(h2, W2, h3);
        spmm_csr_kernel<40, false><<<(N_NODES + 3) / 4, 256, 0, stream>>>(rowptr, edges, h3, out);
    } else {
        // fallback: round-1 atomic path
        zero_f4_kernel<<<2048, 256, 0, stream>>>((float4*)h2, N_NODES * 64 / 4);
        gemm1_kernel<<<(N_NODES + BM - 1) / BM, 128, 0, stream>>>(x, W1, h1);
        spmm1_atomic_kernel<<<N_EDGES / 4, 256, 0, stream>>>(adj_row, adj_col, adj_val, h1, h2);
        gemm2_kernel<true><<<(N_NODES + 7) / 8, 320, 0, stream>>>(h2, W2, h3);
        zero_f4_kernel<<<2048, 256, 0, stream>>>((float4*)out, N_NODES * 40 / 4);
        spmm2_atomic_kernel<<<N_EDGES / 8, 320, 0, stream>>>(adj_row, adj_col, adj_val, h3, out);
    }
}

// Round 3
// 790.071 us; speedup vs baseline: 1.8259x; 1.1781x over previous
//
#include <hip/hip_runtime.h>

#define N_NODES 100000
#define N_EDGES 3200000
#define SCAN_NB 391   // ceil(N_NODES/256)

// ---------------- zero kernels ----------------
__global__ __launch_bounds__(256) void zero_f4_kernel(float4* __restrict__ p, int n4) {
    int i = blockIdx.x * blockDim.x + threadIdx.x;
    int stride = gridDim.x * blockDim.x;
    for (; i < n4; i += stride) p[i] = make_float4(0.f, 0.f, 0.f, 0.f);
}

__global__ __launch_bounds__(256) void zero_int_kernel(int* __restrict__ p, int n) {
    int i = blockIdx.x * 256 + threadIdx.x;
    if (i < n) p[i] = 0;
}

// ---------------- CSR build ----------------
// 8 edges per thread, int4 loads, 8 independent atomic chains for ILP
__global__ __launch_bounds__(256) void hist_kernel(const int* __restrict__ row,
                                                   int* __restrict__ deg) {
    const long base = ((long)blockIdx.x * 256 + threadIdx.x) * 8;
    if (base >= N_EDGES) return;
    int4 r0 = *reinterpret_cast<const int4*>(row + base);
    int4 r1 = *reinterpret_cast<const int4*>(row + base + 4);
    atomicAdd(&deg[r0.x], 1);
    atomicAdd(&deg[r0.y], 1);
    atomicAdd(&deg[r0.z], 1);
    atomicAdd(&deg[r0.w], 1);
    atomicAdd(&deg[r1.x], 1);
    atomicAdd(&deg[r1.y], 1);
    atomicAdd(&deg[r1.z], 1);
    atomicAdd(&deg[r1.w], 1);
}

__global__ __launch_bounds__(256) void scan_a_kernel(const int* __restrict__ deg,
                                                     int* __restrict__ rowptr,
                                                     int* __restrict__ partials) {
    __shared__ int sm[256];
    const int tid = threadIdx.x;
    const int i = blockIdx.x * 256 + tid;
    int v = (i < N_NODES) ? deg[i] : 0;
    sm[tid] = v;
    __syncthreads();
    #pragma unroll
    for (int off = 1; off < 256; off <<= 1) {
        int t = (tid >= off) ? sm[tid - off] : 0;
        __syncthreads();
        sm[tid] += t;
        __syncthreads();
    }
    if (i < N_NODES) rowptr[i] = sm[tid] - v;   // block-local exclusive
    if (tid == 255) partials[blockIdx.x] = sm[255];
}

__global__ __launch_bounds__(512) void scan_b_kernel(int* __restrict__ partials,
                                                     int* __restrict__ rowptr) {
    __shared__ int sm[512];
    const int tid = threadIdx.x;
    int v = (tid < SCAN_NB) ? partials[tid] : 0;
    sm[tid] = v;
    __syncthreads();
    #pragma unroll
    for (int off = 1; off < 512; off <<= 1) {
        int t = (tid >= off) ? sm[tid - off] : 0;
        __syncthreads();
        sm[tid] += t;
        __syncthreads();
    }
    if (tid < SCAN_NB) partials[tid] = sm[tid] - v;  // exclusive block bases
    if (tid == 511) rowptr[N_NODES] = sm[511];       // grand total (= N_EDGES)
}

__global__ __launch_bounds__(256) void scan_c_kernel(int* __restrict__ rowptr,
                                                     int* __restrict__ cursor,
                                                     const int* __restrict__ partials) {
    int i = blockIdx.x * 256 + threadIdx.x;
    if (i < N_NODES) {
        int v = rowptr[i] + partials[blockIdx.x];
        rowptr[i] = v;
        cursor[i] = v;
    }
}

__global__ __launch_bounds__(256) void scatter_kernel(const int* __restrict__ row,
                                                      const int* __restrict__ col,
                                                      const float* __restrict__ val,
                                                      int* __restrict__ cursor,
                                                      int2* __restrict__ edges) {
    const long base = ((long)blockIdx.x * 256 + threadIdx.x) * 8;
    if (base >= N_EDGES) return;
    int4 r0 = *reinterpret_cast<const int4*>(row + base);
    int4 r1 = *reinterpret_cast<const int4*>(row + base + 4);
    int4 c0 = *reinterpret_cast<const int4*>(col + base);
    int4 c1 = *reinterpret_cast<const int4*>(col + base + 4);
    int4 v0 = *reinterpret_cast<const int4*>(reinterpret_cast<const int*>(val) + base);
    int4 v1 = *reinterpret_cast<const int4*>(reinterpret_cast<const int*>(val) + base + 4);
    // 8 independent atomic chains — deep pipeline
    int i0 = atomicAdd(&cursor[r0.x], 1);
    int i1 = atomicAdd(&cursor[r0.y], 1);
    int i2 = atomicAdd(&cursor[r0.z], 1);
    int i3 = atomicAdd(&cursor[r0.w], 1);
    int i4 = atomicAdd(&cursor[r1.x], 1);
    int i5 = atomicAdd(&cursor[r1.y], 1);
    int i6 = atomicAdd(&cursor[r1.z], 1);
    int i7 = atomicAdd(&cursor[r1.w], 1);
    edges[i0] = make_int2(c0.x, v0.x);
    edges[i1] = make_int2(c0.y, v0.y);
    edges[i2] = make_int2(c0.z, v0.z);
    edges[i3] = make_int2(c0.w, v0.w);
    edges[i4] = make_int2(c1.x, v1.x);
    edges[i5] = make_int2(c1.y, v1.y);
    edges[i6] = make_int2(c1.z, v1.z);
    edges[i7] = make_int2(c1.w, v1.w);
}

// ---------------- CSR pull-mode SPMM: one wave per row, unroll-4 gathers ----------------
template<int D, bool RELU>
__global__ __launch_bounds__(256) void spmm_csr_kernel(const int* __restrict__ rowptr,
                                                       const int2* __restrict__ edges,
                                                       const float* __restrict__ H,
                                                       float* __restrict__ O) {
    const int r = blockIdx.x * 4 + (threadIdx.x >> 6);
    if (r >= N_NODES) return;
    const int lane = threadIdx.x & 63;
    const int start = rowptr[r];
    const int end = rowptr[r + 1];
    float acc = 0.f;
    for (int base = start; base < end; base += 64) {
        const int n = end - base;
        int c = 0;
        float v = 0.f;
        if (lane < n) {
            int2 ev = edges[base + lane];
            c = ev.x;
            v = __int_as_float(ev.y);
        }
        const int cnt = n < 64 ? n : 64;
        const int cnt4 = (cnt + 3) & ~3;
        for (int j = 0; j < cnt4; j += 4) {
            // j is wave-uniform -> scalar broadcast; lanes>=cnt contribute v=0
            int c0 = __builtin_amdgcn_readlane(c, j);
            int c1 = __builtin_amdgcn_readlane(c, j + 1);
            int c2 = __builtin_amdgcn_readlane(c, j + 2);
            int c3 = __builtin_amdgcn_readlane(c, j + 3);
            float v0 = __int_as_float(__builtin_amdgcn_readlane(__float_as_int(v), j));
            float v1 = __int_as_float(__builtin_amdgcn_readlane(__float_as_int(v), j + 1));
            float v2 = __int_as_float(__builtin_amdgcn_readlane(__float_as_int(v), j + 2));
            float v3 = __int_as_float(__builtin_amdgcn_readlane(__float_as_int(v), j + 3));
            // 4 independent gathers in flight (unguarded: lanes>=D read owned scratch)
            float h0 = H[(long)c0 * D + lane];
            float h1 = H[(long)c1 * D + lane];
            float h2 = H[(long)c2 * D + lane];
            float h3 = H[(long)c3 * D + lane];
            acc += v0 * h0;
            acc += v1 * h1;
            acc += v2 * h2;
            acc += v3 * h3;
        }
    }
    if (RELU) acc = fmaxf(acc, 0.f);
    if (lane < D) O[(long)r * D + lane] = acc;
}

// ---------------- GEMM1: H1[M,64] = X[M,512] @ W1[512,64] ----------------
#define BM 128
#define BN 64
#define BK 16
__global__ __launch_bounds__(128) void gemm1_kernel(const float* __restrict__ X,
                                                    const float* __restrict__ W1,
                                                    float* __restrict__ H1) {
    __shared__ float As[BK][BM];
    __shared__ float Bs[BK][BN];

    const int tid = threadIdx.x;
    const int mg = tid >> 3;
    const int ng = tid & 7;
    const long row0 = (long)blockIdx.x * BM;

    float4 pa[4];
    float4 pb[2];

    auto loadA = [&](int k0) {
        #pragma unroll
        for (int f = 0; f < 4; ++f) {
            int q = tid + f * 128;
            int r = q >> 2;
            int k4 = (q & 3) << 2;
            long grow = row0 + r;
            if (grow < N_NODES)
                pa[f] = *reinterpret_cast<const float4*>(X + grow * 512 + k0 + k4);
            else
                pa[f] = make_float4(0.f, 0.f, 0.f, 0.f);
        }
    };
    auto loadB = [&](int k0) {
        #pragma unroll
        for (int f = 0; f < 2; ++f) {
            int q = tid + f * 128;
            int kk = q >> 4;
            int j4 = (q & 15) << 2;
            pb[f] = *reinterpret_cast<const float4*>(W1 + (long)(k0 + kk) * 64 + j4);
        }
    };
    auto storeA = [&]() {
        #pragma unroll
        for (int f = 0; f < 4; ++f) {
            int q = tid + f * 128;
            int r = q >> 2;
            int k4 = (q & 3) << 2;
            As[k4 + 0][r] = pa[f].x;
            As[k4 + 1][r] = pa[f].y;
            As[k4 + 2][r] = pa[f].z;
            As[k4 + 3][r] = pa[f].w;
        }
    };
    auto storeB = [&]() {
        #pragma unroll
        for (int f = 0; f < 2; ++f) {
            int q = tid + f * 128;
            int kk = q >> 4;
            int j4 = (q & 15) << 2;
            *reinterpret_cast<float4*>(&Bs[kk][j4]) = pb[f];
        }
    };

    float acc[8][8];
    #pragma unroll
    for (int m = 0; m < 8; ++m)
        #pragma unroll
        for (int n = 0; n < 8; ++n) acc[m][n] = 0.f;

    loadA(0);
    loadB(0);
    storeA();
    storeB();
    __syncthreads();

    for (int k0 = 0; k0 < 512; k0 += BK) {
        const bool has_next = (k0 + BK) < 512;
        if (has_next) { loadA(k0 + BK); loadB(k0 + BK); }

        #pragma unroll
        for (int kk = 0; kk < BK; ++kk) {
            float a[8], b[8];
            *reinterpret_cast<float4*>(&a[0]) = *reinterpret_cast<const float4*>(&As[kk][mg * 8]);
            *reinterpret_cast<float4*>(&a[4]) = *reinterpret_cast<const float4*>(&As[kk][mg * 8 + 4]);
            *reinterpret_cast<float4*>(&b[0]) = *reinterpret_cast<const float4*>(&Bs[kk][ng * 8]);
            *reinterpret_cast<float4*>(&b[4]) = *reinterpret_cast<const float4*>(&Bs[kk][ng * 8 + 4]);
            #pragma unroll
            for (int m = 0; m < 8; ++m)
                #pragma unroll
                for (int n = 0; n < 8; ++n) acc[m][n] += a[m] * b[n];
        }
        __syncthreads();
        if (has_next) {
            storeA();
            storeB();
            __syncthreads();
        }
    }

    #pragma unroll
    for (int m = 0; m < 8; ++m) {
        long grow = row0 + mg * 8 + m;
        if (grow < N_NODES) {
            #pragma unroll
            for (int n = 0; n < 8; n += 4) {
                *reinterpret_cast<float4*>(H1 + grow * 64 + ng * 8 + n) =
                    make_float4(acc[m][n], acc[m][n + 1], acc[m][n + 2], acc[m][n + 3]);
            }
        }
    }
}

// ---------------- GEMM2: H3[M,40] = (optionally relu)(H2[M,64]) @ W2[64,40] ----------------
template<bool RELU_IN>
__global__ __launch_bounds__(320) void gemm2_kernel(const float* __restrict__ H2,
                                                    const float* __restrict__ W2,
                                                    float* __restrict__ H3) {
    __shared__ float hs[8 * 64];
    __shared__ float ws[64 * 40];
    const int r0 = blockIdx.x * 8;

    for (int i = threadIdx.x; i < 8 * 64; i += 320) {
        int r = r0 + (i >> 6);
        float v = (r < N_NODES) ? H2[(long)r * 64 + (i & 63)] : 0.f;
        if (RELU_IN) v = v > 0.f ? v : 0.f;
        hs[i] = v;
    }
    for (int i = threadIdx.x; i < 64 * 40; i += 320) ws[i] = W2[i];
    __syncthreads();

    const int rl = threadIdx.x / 40;
    const int d = threadIdx.x % 40;
    float acc = 0.f;
    #pragma unroll
    for (int k = 0; k < 64; ++k) acc += hs[rl * 64 + k] * ws[k * 40 + d];

    const int r = r0 + rl;
    if (r < N_NODES) H3[(long)r * 40 + d] = acc;
}

// ---------------- fallback atomic SPMMs (used only if ws too small) ----------------
__global__ __launch_bounds__(256) void spmm1_atomic_kernel(const int* __restrict__ row,
                                                           const int* __restrict__ col,
                                                           const float* __restrict__ val,
                                                           const float* __restrict__ H1,
                                                           float* __restrict__ H2) {
    int e = blockIdx.x * 4 + (threadIdx.x >> 6);
    int lane = threadIdx.x & 63;
    if (e >= N_EDGES) return;
    atomicAdd(H2 + (long)row[e] * 64 + lane, val[e] * H1[(long)col[e] * 64 + lane]);
}

__global__ __launch_bounds__(320) void spmm2_atomic_kernel(const int* __restrict__ row,
                                                           const int* __restrict__ col,
                                                           const float* __restrict__ val,
                                                           const float* __restrict__ H3,
                                                           float* __restrict__ OUT) {
    int e = blockIdx.x * 8 + threadIdx.x / 40;
    int d = threadIdx.x % 40;
    if (e >= N_EDGES) return;
    atomicAdd(OUT + (long)row[e] * 40 + d, val[e] * H3[(long)col[e] * 40 + d]);
}

extern "C" void kernel_launch(void* const* d_in, const int* in_sizes, int n_in,
                              void* d_out, int out_size, void* d_ws, size_t ws_size,
                              hipStream_t stream) {
    const float* x       = (const float*)d_in[0];
    const float* W1      = (const float*)d_in[1];
    const float* W2      = (const float*)d_in[2];
    const float* adj_val = (const float*)d_in[3];
    const int*   adj_row = (const int*)d_in[4];
    const int*   adj_col = (const int*)d_in[5];
    float* out = (float*)d_out;

    char* ws = (char*)d_ws;
    const size_t OFF_H1     = 0;                       // 25.6 MB (h3 reuses this after spmm1)
    const size_t OFF_H2     = 25600000;                // 25.6 MB
    const size_t OFF_EDGES  = 51200000;                // 25.6 MB (int2 col+val, CSR order)
    const size_t OFF_ROWPTR = 76800000;                // 400,004 B
    const size_t OFF_CURSOR = 77200016;                // 400,000 B
    const size_t OFF_DEG    = 77600016;                // 400,000 B
    const size_t OFF_PART   = 78000016;                // 2,048 B
    const size_t WS_NEED    = 78002064;

    float* h1     = (float*)(ws + OFF_H1);
    float* h2     = (float*)(ws + OFF_H2);
    float* h3     = (float*)(ws + OFF_H1);  // overlays h1 (dead after spmm1)
    int2*  edges  = (int2*)(ws + OFF_EDGES);
    int*   rowptr = (int*)(ws + OFF_ROWPTR);
    int*   cursor = (int*)(ws + OFF_CURSOR);
    int*   deg    = (int*)(ws + OFF_DEG);
    int*   part   = (int*)(ws + OFF_PART);

    if (ws_size >= WS_NEED) {
        // ---- CSR build ----
        zero_int_kernel<<<SCAN_NB, 256, 0, stream>>>(deg, N_NODES);
        hist_kernel<<<(N_EDGES / 8 + 255) / 256, 256, 0, stream>>>(adj_row, deg);
        scan_a_kernel<<<SCAN_NB, 256, 0, stream>>>(deg, rowptr, part);
        scan_b_kernel<<<1, 512, 0, stream>>>(part, rowptr);
        scan_c_kernel<<<SCAN_NB, 256, 0, stream>>>(rowptr, cursor, part);
        scatter_kernel<<<(N_EDGES / 8 + 255) / 256, 256, 0, stream>>>(adj_row, adj_col, adj_val, cursor, edges);

        // ---- dense + sparse pipeline ----
        gemm1_kernel<<<(N_NODES + BM - 1) / BM, 128, 0, stream>>>(x, W1, h1);
        spmm_csr_kernel<64, true><<<(N_NODES + 3) / 4, 256, 0, stream>>>(rowptr, edges, h1, h2);
        gemm2_kernel<false><<<(N_NODES + 7) / 8, 320, 0, stream>>>(h2, W2, h3);
        spmm_csr_kernel<40, false><<<(N_NODES + 3) / 4, 256, 0, stream>>>(rowptr, edges, h3, out);
    } else {
        // fallback: round-1 atomic path
        zero_f4_kernel<<<2048, 256, 0, stream>>>((float4*)h2, N_NODES * 64 / 4);
        gemm1_kernel<<<(N_NODES + BM - 1) / BM, 128, 0, stream>>>(x, W1, h1);
        spmm1_atomic_kernel<<<N_EDGES / 4, 256, 0, stream>>>(adj_row, adj_col, adj_val, h1, h2);
        gemm2_kernel<true><<<(N_NODES + 7) / 8, 320, 0, stream>>>(h2, W2, h3);
        zero_f4_kernel<<<2048, 256, 0, stream>>>((float4*)out, N_NODES * 40 / 4);
        spmm2_atomic_kernel<<<N_EDGES / 8, 320, 0, stream>>>(adj_row, adj_col, adj_val, h3, out);
    }
}

// Round 4
// 525.058 us; speedup vs baseline: 2.7475x; 1.5047x over previous
//
#include <hip/hip_runtime.h>

#define N_NODES 100000
#define N_EDGES 3200000
#define SCAN_NB 391   // ceil(N_NODES/256)

typedef unsigned int uint;
typedef unsigned short ushort;

// bf16 helpers (manual, RNE)
static __device__ __forceinline__ ushort f2bf(float f) {
    uint u = __float_as_uint(f);
    u += 0x7fffu + ((u >> 16) & 1u);
    return (ushort)(u >> 16);
}
static __device__ __forceinline__ float bf2f(ushort h) {
    return __uint_as_float(((uint)h) << 16);
}

// ---------------- zero kernel ----------------
__global__ __launch_bounds__(256) void zero_int_kernel(int* __restrict__ p, int n) {
    int i = blockIdx.x * 256 + threadIdx.x;
    if (i < n) p[i] = 0;
}

// ---------------- CSR build ----------------
// hist: 8 edges/thread; atomic return value IS the within-row rank
__global__ __launch_bounds__(256) void hist_kernel(const int* __restrict__ row,
                                                   int* __restrict__ deg,
                                                   int* __restrict__ rank) {
    const long base = ((long)blockIdx.x * 256 + threadIdx.x) * 8;
    if (base >= N_EDGES) return;
    int4 r0 = *reinterpret_cast<const int4*>(row + base);
    int4 r1 = *reinterpret_cast<const int4*>(row + base + 4);
    int4 k0, k1;
    k0.x = atomicAdd(&deg[r0.x], 1);
    k0.y = atomicAdd(&deg[r0.y], 1);
    k0.z = atomicAdd(&deg[r0.z], 1);
    k0.w = atomicAdd(&deg[r0.w], 1);
    k1.x = atomicAdd(&deg[r1.x], 1);
    k1.y = atomicAdd(&deg[r1.y], 1);
    k1.z = atomicAdd(&deg[r1.z], 1);
    k1.w = atomicAdd(&deg[r1.w], 1);
    *reinterpret_cast<int4*>(rank + base) = k0;
    *reinterpret_cast<int4*>(rank + base + 4) = k1;
}

__global__ __launch_bounds__(256) void scan_a_kernel(const int* __restrict__ deg,
                                                     int* __restrict__ rowptr,
                                                     int* __restrict__ partials) {
    __shared__ int sm[256];
    const int tid = threadIdx.x;
    const int i = blockIdx.x * 256 + tid;
    int v = (i < N_NODES) ? deg[i] : 0;
    sm[tid] = v;
    __syncthreads();
    #pragma unroll
    for (int off = 1; off < 256; off <<= 1) {
        int t = (tid >= off) ? sm[tid - off] : 0;
        __syncthreads();
        sm[tid] += t;
        __syncthreads();
    }
    if (i < N_NODES) rowptr[i] = sm[tid] - v;   // block-local exclusive
    if (tid == 255) partials[blockIdx.x] = sm[255];
}

__global__ __launch_bounds__(512) void scan_b_kernel(int* __restrict__ partials,
                                                     int* __restrict__ rowptr) {
    __shared__ int sm[512];
    const int tid = threadIdx.x;
    int v = (tid < SCAN_NB) ? partials[tid] : 0;
    sm[tid] = v;
    __syncthreads();
    #pragma unroll
    for (int off = 1; off < 512; off <<= 1) {
        int t = (tid >= off) ? sm[tid - off] : 0;
        __syncthreads();
        sm[tid] += t;
        __syncthreads();
    }
    if (tid < SCAN_NB) partials[tid] = sm[tid] - v;  // exclusive block bases
    if (tid == 511) rowptr[N_NODES] = sm[511];       // grand total (= N_EDGES)
}

__global__ __launch_bounds__(256) void scan_c_kernel(int* __restrict__ rowptr,
                                                     const int* __restrict__ partials) {
    int i = blockIdx.x * 256 + threadIdx.x;
    if (i < N_NODES) rowptr[i] += partials[blockIdx.x];
}

// scatter: atomic-free. slot = rowptr[row] + rank. 8 edges/thread.
__global__ __launch_bounds__(256) void scatter_kernel(const int* __restrict__ row,
                                                      const int* __restrict__ col,
                                                      const float* __restrict__ val,
                                                      const int* __restrict__ rowptr,
                                                      const int* __restrict__ rank,
                                                      int2* __restrict__ edges) {
    const long base = ((long)blockIdx.x * 256 + threadIdx.x) * 8;
    if (base >= N_EDGES) return;
    int4 r0 = *reinterpret_cast<const int4*>(row + base);
    int4 r1 = *reinterpret_cast<const int4*>(row + base + 4);
    int4 c0 = *reinterpret_cast<const int4*>(col + base);
    int4 c1 = *reinterpret_cast<const int4*>(col + base + 4);
    int4 v0 = *reinterpret_cast<const int4*>(reinterpret_cast<const int*>(val) + base);
    int4 v1 = *reinterpret_cast<const int4*>(reinterpret_cast<const int*>(val) + base + 4);
    int4 k0 = *reinterpret_cast<const int4*>(rank + base);
    int4 k1 = *reinterpret_cast<const int4*>(rank + base + 4);
    // 8 independent read->write chains, no atomics
    int s0 = rowptr[r0.x] + k0.x;
    int s1 = rowptr[r0.y] + k0.y;
    int s2 = rowptr[r0.z] + k0.z;
    int s3 = rowptr[r0.w] + k0.w;
    int s4 = rowptr[r1.x] + k1.x;
    int s5 = rowptr[r1.y] + k1.y;
    int s6 = rowptr[r1.z] + k1.z;
    int s7 = rowptr[r1.w] + k1.w;
    edges[s0] = make_int2(c0.x, v0.x);
    edges[s1] = make_int2(c0.y, v0.y);
    edges[s2] = make_int2(c0.z, v0.z);
    edges[s3] = make_int2(c0.w, v0.w);
    edges[s4] = make_int2(c1.x, v1.x);
    edges[s5] = make_int2(c1.y, v1.y);
    edges[s6] = make_int2(c1.z, v1.z);
    edges[s7] = make_int2(c1.w, v1.w);
}

// ---------------- CSR pull-mode SPMM: one wave per row, bf16 H, fp32 out ----------------
template<int D, bool RELU>
__global__ __launch_bounds__(256) void spmm_csr_kernel(const int* __restrict__ rowptr,
                                                       const int2* __restrict__ edges,
                                                       const ushort* __restrict__ H,
                                                       float* __restrict__ O) {
    const int r = blockIdx.x * 4 + (threadIdx.x >> 6);
    if (r >= N_NODES) return;
    const int lane = threadIdx.x & 63;
    const int start = rowptr[r];
    const int end = rowptr[r + 1];
    float acc = 0.f;
    for (int base = start; base < end; base += 64) {
        const int n = end - base;
        int c = 0;
        float v = 0.f;
        if (lane < n) {
            int2 ev = edges[base + lane];
            c = ev.x;
            v = __int_as_float(ev.y);
        }
        const int cnt = n < 64 ? n : 64;
        const int cnt4 = (cnt + 3) & ~3;
        for (int j = 0; j < cnt4; j += 4) {
            int c0 = __builtin_amdgcn_readlane(c, j);
            int c1 = __builtin_amdgcn_readlane(c, j + 1);
            int c2 = __builtin_amdgcn_readlane(c, j + 2);
            int c3 = __builtin_amdgcn_readlane(c, j + 3);
            float v0 = __int_as_float(__builtin_amdgcn_readlane(__float_as_int(v), j));
            float v1 = __int_as_float(__builtin_amdgcn_readlane(__float_as_int(v), j + 1));
            float v2 = __int_as_float(__builtin_amdgcn_readlane(__float_as_int(v), j + 2));
            float v3 = __int_as_float(__builtin_amdgcn_readlane(__float_as_int(v), j + 3));
            // 4 independent bf16 gathers in flight (unguarded; overreads stay in ws)
            ushort h0 = H[(long)c0 * D + lane];
            ushort h1 = H[(long)c1 * D + lane];
            ushort h2 = H[(long)c2 * D + lane];
            ushort h3 = H[(long)c3 * D + lane];
            acc += v0 * bf2f(h0);
            acc += v1 * bf2f(h1);
            acc += v2 * bf2f(h2);
            acc += v3 * bf2f(h3);
        }
    }
    if (RELU) acc = fmaxf(acc, 0.f);
    if (lane < D) O[(long)r * D + lane] = acc;
}

// ---------------- GEMM1: H1[M,64] (bf16) = X[M,512] @ W1[512,64] ----------------
#define BM 128
#define BN 64
#define BK 16
__global__ __launch_bounds__(128) void gemm1_kernel(const float* __restrict__ X,
                                                    const float* __restrict__ W1,
                                                    ushort* __restrict__ H1) {
    __shared__ float As[BK][BM];
    __shared__ float Bs[BK][BN];

    const int tid = threadIdx.x;
    const int mg = tid >> 3;
    const int ng = tid & 7;
    const long row0 = (long)blockIdx.x * BM;

    float4 pa[4];
    float4 pb[2];

    auto loadA = [&](int k0) {
        #pragma unroll
        for (int f = 0; f < 4; ++f) {
            int q = tid + f * 128;
            int r = q >> 2;
            int k4 = (q & 3) << 2;
            long grow = row0 + r;
            if (grow < N_NODES)
                pa[f] = *reinterpret_cast<const float4*>(X + grow * 512 + k0 + k4);
            else
                pa[f] = make_float4(0.f, 0.f, 0.f, 0.f);
        }
    };
    auto loadB = [&](int k0) {
        #pragma unroll
        for (int f = 0; f < 2; ++f) {
            int q = tid + f * 128;
            int kk = q >> 4;
            int j4 = (q & 15) << 2;
            pb[f] = *reinterpret_cast<const float4*>(W1 + (long)(k0 + kk) * 64 + j4);
        }
    };
    auto storeA = [&]() {
        #pragma unroll
        for (int f = 0; f < 4; ++f) {
            int q = tid + f * 128;
            int r = q >> 2;
            int k4 = (q & 3) << 2;
            As[k4 + 0][r] = pa[f].x;
            As[k4 + 1][r] = pa[f].y;
            As[k4 + 2][r] = pa[f].z;
            As[k4 + 3][r] = pa[f].w;
        }
    };
    auto storeB = [&]() {
        #pragma unroll
        for (int f = 0; f < 2; ++f) {
            int q = tid + f * 128;
            int kk = q >> 4;
            int j4 = (q & 15) << 2;
            *reinterpret_cast<float4*>(&Bs[kk][j4]) = pb[f];
        }
    };

    float acc[8][8];
    #pragma unroll
    for (int m = 0; m < 8; ++m)
        #pragma unroll
        for (int n = 0; n < 8; ++n) acc[m][n] = 0.f;

    loadA(0);
    loadB(0);
    storeA();
    storeB();
    __syncthreads();

    for (int k0 = 0; k0 < 512; k0 += BK) {
        const bool has_next = (k0 + BK) < 512;
        if (has_next) { loadA(k0 + BK); loadB(k0 + BK); }

        #pragma unroll
        for (int kk = 0; kk < BK; ++kk) {
            float a[8], b[8];
            *reinterpret_cast<float4*>(&a[0]) = *reinterpret_cast<const float4*>(&As[kk][mg * 8]);
            *reinterpret_cast<float4*>(&a[4]) = *reinterpret_cast<const float4*>(&As[kk][mg * 8 + 4]);
            *reinterpret_cast<float4*>(&b[0]) = *reinterpret_cast<const float4*>(&Bs[kk][ng * 8]);
            *reinterpret_cast<float4*>(&b[4]) = *reinterpret_cast<const float4*>(&Bs[kk][ng * 8 + 4]);
            #pragma unroll
            for (int m = 0; m < 8; ++m)
                #pragma unroll
                for (int n = 0; n < 8; ++n) acc[m][n] += a[m] * b[n];
        }
        __syncthreads();
        if (has_next) {
            storeA();
            storeB();
            __syncthreads();
        }
    }

    #pragma unroll
    for (int m = 0; m < 8; ++m) {
        long grow = row0 + mg * 8 + m;
        if (grow < N_NODES) {
            uint4 o;
            o.x = (uint)f2bf(acc[m][0]) | ((uint)f2bf(acc[m][1]) << 16);
            o.y = (uint)f2bf(acc[m][2]) | ((uint)f2bf(acc[m][3]) << 16);
            o.z = (uint)f2bf(acc[m][4]) | ((uint)f2bf(acc[m][5]) << 16);
            o.w = (uint)f2bf(acc[m][6]) | ((uint)f2bf(acc[m][7]) << 16);
            *reinterpret_cast<uint4*>(H1 + grow * 64 + ng * 8) = o;
        }
    }
}

// ---------------- GEMM2: H3[M,40] (bf16) = relu-free (H2 fp32 [M,64]) @ W2[64,40] ----------------
__global__ __launch_bounds__(320) void gemm2_kernel(const float* __restrict__ H2,
                                                    const float* __restrict__ W2,
                                                    ushort* __restrict__ H3) {
    __shared__ float hs[8 * 64];
    __shared__ float ws[64 * 40];
    const int r0 = blockIdx.x * 8;

    for (int i = threadIdx.x; i < 8 * 64; i += 320) {
        int r = r0 + (i >> 6);
        hs[i] = (r < N_NODES) ? H2[(long)r * 64 + (i & 63)] : 0.f;
    }
    for (int i = threadIdx.x; i < 64 * 40; i += 320) ws[i] = W2[i];
    __syncthreads();

    const int rl = threadIdx.x / 40;
    const int d = threadIdx.x % 40;
    float acc = 0.f;
    #pragma unroll
    for (int k = 0; k < 64; ++k) acc += hs[rl * 64 + k] * ws[k * 40 + d];

    const int r = r0 + rl;
    if (r < N_NODES) H3[(long)r * 40 + d] = f2bf(acc);
}

extern "C" void kernel_launch(void* const* d_in, const int* in_sizes, int n_in,
                              void* d_out, int out_size, void* d_ws, size_t ws_size,
                              hipStream_t stream) {
    const float* x       = (const float*)d_in[0];
    const float* W1      = (const float*)d_in[1];
    const float* W2      = (const float*)d_in[2];
    const float* adj_val = (const float*)d_in[3];
    const int*   adj_row = (const int*)d_in[4];
    const int*   adj_col = (const int*)d_in[5];
    float* out = (float*)d_out;

    char* ws = (char*)d_ws;
    const size_t OFF_H1     = 0;            // bf16 h1: 12.8 MB (h3 bf16 8 MB overlays after spmm1)
    const size_t OFF_H2     = 12800000;     // fp32 h2: 25.6 MB
    const size_t OFF_EDGES  = 38400000;     // int2 edges: 25.6 MB
    const size_t OFF_RANK   = 64000000;     // int rank: 12.8 MB
    const size_t OFF_ROWPTR = 76800000;     // 400,004 B
    const size_t OFF_DEG    = 77200016;     // 400,000 B
    const size_t OFF_PART   = 77600016;     // 2,048 B

    ushort* h1     = (ushort*)(ws + OFF_H1);
    float*  h2     = (float*)(ws + OFF_H2);
    ushort* h3     = (ushort*)(ws + OFF_H1);   // overlays h1 (dead after spmm1)
    int2*   edges  = (int2*)(ws + OFF_EDGES);
    int*    rank   = (int*)(ws + OFF_RANK);
    int*    rowptr = (int*)(ws + OFF_ROWPTR);
    int*    deg    = (int*)(ws + OFF_DEG);
    int*    part   = (int*)(ws + OFF_PART);

    // gemm1 first: stream x (205 MB) through L3 before building the CSR
    // working set, so edges/rank/h1 stay L3-resident for the spmms.
    gemm1_kernel<<<(N_NODES + BM - 1) / BM, 128, 0, stream>>>(x, W1, h1);

    // ---- CSR build (atomic-free scatter) ----
    zero_int_kernel<<<SCAN_NB, 256, 0, stream>>>(deg, N_NODES);
    hist_kernel<<<(N_EDGES / 8 + 255) / 256, 256, 0, stream>>>(adj_row, deg, rank);
    scan_a_kernel<<<SCAN_NB, 256, 0, stream>>>(deg, rowptr, part);
    scan_b_kernel<<<1, 512, 0, stream>>>(part, rowptr);
    scan_c_kernel<<<SCAN_NB, 256, 0, stream>>>(rowptr, part);
    scatter_kernel<<<(N_EDGES / 8 + 255) / 256, 256, 0, stream>>>(adj_row, adj_col, adj_val,
                                                                  rowptr, rank, edges);

    // ---- sparse pipeline ----
    spmm_csr_kernel<64, true><<<(N_NODES + 3) / 4, 256, 0, stream>>>(rowptr, edges, h1, h2);
    gemm2_kernel<<<(N_NODES + 7) / 8, 320, 0, stream>>>(h2, W2, h3);
    spmm_csr_kernel<40, false><<<(N_NODES + 3) / 4, 256, 0, stream>>>(rowptr, edges, h3, out);
}

// Round 5
// 454.978 us; speedup vs baseline: 3.1707x; 1.1540x over previous
//
#include <hip/hip_runtime.h>

#define N_NODES 100000
#define N_EDGES 3200000
#define SCAN_NB 391   // ceil(N_NODES/256)

typedef unsigned int uint;
typedef unsigned short ushort;

typedef __attribute__((ext_vector_type(8))) short short8;    // 8 bf16 (4 VGPRs)
typedef __attribute__((ext_vector_type(4))) float floatx4;   // MFMA C/D

// bf16 helpers
static __device__ __forceinline__ ushort f2bf(float f) {     // RNE
    uint u = __float_as_uint(f);
    u += 0x7fffu + ((u >> 16) & 1u);
    return (ushort)(u >> 16);
}
static __device__ __forceinline__ float bf2f(ushort h) {
    return __uint_as_float(((uint)h) << 16);
}

// ---------------- zero kernel ----------------
__global__ __launch_bounds__(256) void zero_int_kernel(int* __restrict__ p, int n) {
    int i = blockIdx.x * 256 + threadIdx.x;
    if (i < n) p[i] = 0;
}

// ---------------- W1 -> bf16 fragment-ordered ----------------
// dest t: j = t&7, lane = (t>>3)&63, tile = t>>9; kt = tile>>2, nt = tile&3
// src: k = kt*32 + (lane>>4)*8 + j ; n = nt*16 + (lane&15)
__global__ __launch_bounds__(256) void w1cvt_kernel(const float* __restrict__ W1,
                                                    ushort* __restrict__ W1f) {
    int t = blockIdx.x * 256 + threadIdx.x;   // 0..32767
    int j = t & 7;
    int lane = (t >> 3) & 63;
    int tile = t >> 9;
    int kt = tile >> 2, nt = tile & 3;
    int k = kt * 32 + ((lane >> 4) << 3) + j;
    int n = nt * 16 + (lane & 15);
    W1f[t] = f2bf(W1[k * 64 + n]);
}

// ---------------- GEMM1 (MFMA): H1[M,64] (bf16) = X[M,512] @ W1[512,64] ----------------
// 256 thr = 4 waves; wave computes 16 rows x 64 cols; no LDS.
__global__ __launch_bounds__(256) void gemm1_mfma_kernel(const float* __restrict__ X,
                                                         const ushort* __restrict__ W1f,
                                                         ushort* __restrict__ H1) {
    const int tid = threadIdx.x;
    const int wave = tid >> 6;
    const int lane = tid & 63;
    const int row = blockIdx.x * 64 + wave * 16 + (lane & 15);   // A-operand row
    const bool valid = row < N_NODES;
    const float* xr = X + (long)row * 512 + ((lane >> 4) << 3);
    const short8* bb = reinterpret_cast<const short8*>(W1f) + lane;

    floatx4 acc0 = {0.f, 0.f, 0.f, 0.f};
    floatx4 acc1 = {0.f, 0.f, 0.f, 0.f};
    floatx4 acc2 = {0.f, 0.f, 0.f, 0.f};
    floatx4 acc3 = {0.f, 0.f, 0.f, 0.f};

    for (int kt = 0; kt < 16; ++kt) {
        float4 ax0, ax1;
        if (valid) {
            ax0 = *reinterpret_cast<const float4*>(xr + kt * 32);
            ax1 = *reinterpret_cast<const float4*>(xr + kt * 32 + 4);
        } else {
            ax0 = make_float4(0.f, 0.f, 0.f, 0.f);
            ax1 = ax0;
        }
        // pack 8 fp32 -> 8 bf16 (truncate)
        uint4 ap;
        ap.x = (__float_as_uint(ax0.x) >> 16) | (__float_as_uint(ax0.y) & 0xffff0000u);
        ap.y = (__float_as_uint(ax0.z) >> 16) | (__float_as_uint(ax0.w) & 0xffff0000u);
        ap.z = (__float_as_uint(ax1.x) >> 16) | (__float_as_uint(ax1.y) & 0xffff0000u);
        ap.w = (__float_as_uint(ax1.z) >> 16) | (__float_as_uint(ax1.w) & 0xffff0000u);
        short8 a = *reinterpret_cast<short8*>(&ap);

        const short8* bk = bb + kt * 4 * 64;
        acc0 = __builtin_amdgcn_mfma_f32_16x16x32_bf16(a, bk[0 * 64], acc0, 0, 0, 0);
        acc1 = __builtin_amdgcn_mfma_f32_16x16x32_bf16(a, bk[1 * 64], acc1, 0, 0, 0);
        acc2 = __builtin_amdgcn_mfma_f32_16x16x32_bf16(a, bk[2 * 64], acc2, 0, 0, 0);
        acc3 = __builtin_amdgcn_mfma_f32_16x16x32_bf16(a, bk[3 * 64], acc3, 0, 0, 0);
    }

    // C/D: col = lane&15 (+nt*16), row = base + (lane>>4)*4 + reg
    const int mrow = blockIdx.x * 64 + wave * 16 + (lane >> 4) * 4;
    const int ncol = lane & 15;
    #pragma unroll
    for (int r = 0; r < 4; ++r) {
        int orow = mrow + r;
        if (orow < N_NODES) {
            ushort* o = H1 + (long)orow * 64 + ncol;
            o[0]  = f2bf(acc0[r]);
            o[16] = f2bf(acc1[r]);
            o[32] = f2bf(acc2[r]);
            o[48] = f2bf(acc3[r]);
        }
    }
}

// ---------------- CSR build ----------------
__global__ __launch_bounds__(256) void hist_kernel(const int* __restrict__ row,
                                                   int* __restrict__ deg,
                                                   int* __restrict__ rank) {
    const long base = ((long)blockIdx.x * 256 + threadIdx.x) * 8;
    if (base >= N_EDGES) return;
    int4 r0 = *reinterpret_cast<const int4*>(row + base);
    int4 r1 = *reinterpret_cast<const int4*>(row + base + 4);
    int4 k0, k1;
    k0.x = atomicAdd(&deg[r0.x], 1);
    k0.y = atomicAdd(&deg[r0.y], 1);
    k0.z = atomicAdd(&deg[r0.z], 1);
    k0.w = atomicAdd(&deg[r0.w], 1);
    k1.x = atomicAdd(&deg[r1.x], 1);
    k1.y = atomicAdd(&deg[r1.y], 1);
    k1.z = atomicAdd(&deg[r1.z], 1);
    k1.w = atomicAdd(&deg[r1.w], 1);
    *reinterpret_cast<int4*>(rank + base) = k0;
    *reinterpret_cast<int4*>(rank + base + 4) = k1;
}

__global__ __launch_bounds__(256) void scan_a_kernel(const int* __restrict__ deg,
                                                     int* __restrict__ rowptr,
                                                     int* __restrict__ partials) {
    __shared__ int sm[256];
    const int tid = threadIdx.x;
    const int i = blockIdx.x * 256 + tid;
    int v = (i < N_NODES) ? deg[i] : 0;
    sm[tid] = v;
    __syncthreads();
    #pragma unroll
    for (int off = 1; off < 256; off <<= 1) {
        int t = (tid >= off) ? sm[tid - off] : 0;
        __syncthreads();
        sm[tid] += t;
        __syncthreads();
    }
    if (i < N_NODES) rowptr[i] = sm[tid] - v;
    if (tid == 255) partials[blockIdx.x] = sm[255];
}

__global__ __launch_bounds__(512) void scan_b_kernel(int* __restrict__ partials,
                                                     int* __restrict__ rowptr) {
    __shared__ int sm[512];
    const int tid = threadIdx.x;
    int v = (tid < SCAN_NB) ? partials[tid] : 0;
    sm[tid] = v;
    __syncthreads();
    #pragma unroll
    for (int off = 1; off < 512; off <<= 1) {
        int t = (tid >= off) ? sm[tid - off] : 0;
        __syncthreads();
        sm[tid] += t;
        __syncthreads();
    }
    if (tid < SCAN_NB) partials[tid] = sm[tid] - v;
    if (tid == 511) rowptr[N_NODES] = sm[511];
}

__global__ __launch_bounds__(256) void scan_c_kernel(int* __restrict__ rowptr,
                                                     const int* __restrict__ partials) {
    int i = blockIdx.x * 256 + threadIdx.x;
    if (i < N_NODES) rowptr[i] += partials[blockIdx.x];
}

__global__ __launch_bounds__(256) void scatter_kernel(const int* __restrict__ row,
                                                      const int* __restrict__ col,
                                                      const float* __restrict__ val,
                                                      const int* __restrict__ rowptr,
                                                      const int* __restrict__ rank,
                                                      int2* __restrict__ edges) {
    const long base = ((long)blockIdx.x * 256 + threadIdx.x) * 8;
    if (base >= N_EDGES) return;
    int4 r0 = *reinterpret_cast<const int4*>(row + base);
    int4 r1 = *reinterpret_cast<const int4*>(row + base + 4);
    int4 c0 = *reinterpret_cast<const int4*>(col + base);
    int4 c1 = *reinterpret_cast<const int4*>(col + base + 4);
    int4 v0 = *reinterpret_cast<const int4*>(reinterpret_cast<const int*>(val) + base);
    int4 v1 = *reinterpret_cast<const int4*>(reinterpret_cast<const int*>(val) + base + 4);
    int4 k0 = *reinterpret_cast<const int4*>(rank + base);
    int4 k1 = *reinterpret_cast<const int4*>(rank + base + 4);
    int s0 = rowptr[r0.x] + k0.x;
    int s1 = rowptr[r0.y] + k0.y;
    int s2 = rowptr[r0.z] + k0.z;
    int s3 = rowptr[r0.w] + k0.w;
    int s4 = rowptr[r1.x] + k1.x;
    int s5 = rowptr[r1.y] + k1.y;
    int s6 = rowptr[r1.z] + k1.z;
    int s7 = rowptr[r1.w] + k1.w;
    edges[s0] = make_int2(c0.x, v0.x);
    edges[s1] = make_int2(c0.y, v0.y);
    edges[s2] = make_int2(c0.z, v0.z);
    edges[s3] = make_int2(c0.w, v0.w);
    edges[s4] = make_int2(c1.x, v1.x);
    edges[s5] = make_int2(c1.y, v1.y);
    edges[s6] = make_int2(c1.z, v1.z);
    edges[s7] = make_int2(c1.w, v1.w);
}

// ---------------- CSR pull-mode SPMM: one wave per row, bf16 H, fp32 out ----------------
template<int D, bool RELU>
__global__ __launch_bounds__(256) void spmm_csr_kernel(const int* __restrict__ rowptr,
                                                       const int2* __restrict__ edges,
                                                       const ushort* __restrict__ H,
                                                       float* __restrict__ O) {
    const int r = blockIdx.x * 4 + (threadIdx.x >> 6);
    if (r >= N_NODES) return;
    const int lane = threadIdx.x & 63;
    const int start = rowptr[r];
    const int end = rowptr[r + 1];
    float acc = 0.f;
    for (int base = start; base < end; base += 64) {
        const int n = end - base;
        int c = 0;
        float v = 0.f;
        if (lane < n) {
            int2 ev = edges[base + lane];
            c = ev.x;
            v = __int_as_float(ev.y);
        }
        const int cnt = n < 64 ? n : 64;
        const int cnt4 = (cnt + 3) & ~3;
        for (int j = 0; j < cnt4; j += 4) {
            int c0 = __builtin_amdgcn_readlane(c, j);
            int c1 = __builtin_amdgcn_readlane(c, j + 1);
            int c2 = __builtin_amdgcn_readlane(c, j + 2);
            int c3 = __builtin_amdgcn_readlane(c, j + 3);
            float v0 = __int_as_float(__builtin_amdgcn_readlane(__float_as_int(v), j));
            float v1 = __int_as_float(__builtin_amdgcn_readlane(__float_as_int(v), j + 1));
            float v2 = __int_as_float(__builtin_amdgcn_readlane(__float_as_int(v), j + 2));
            float v3 = __int_as_float(__builtin_amdgcn_readlane(__float_as_int(v), j + 3));
            ushort h0 = H[(long)c0 * D + lane];
            ushort h1 = H[(long)c1 * D + lane];
            ushort h2 = H[(long)c2 * D + lane];
            ushort h3 = H[(long)c3 * D + lane];
            acc += v0 * bf2f(h0);
            acc += v1 * bf2f(h1);
            acc += v2 * bf2f(h2);
            acc += v3 * bf2f(h3);
        }
    }
    if (RELU) acc = fmaxf(acc, 0.f);
    if (lane < D) O[(long)r * D + lane] = acc;
}

// ---------------- GEMM2: H3[M,40] (bf16) = H2[M,64] (fp32) @ W2[64,40] ----------------
__global__ __launch_bounds__(320) void gemm2_kernel(const float* __restrict__ H2,
                                                    const float* __restrict__ W2,
                                                    ushort* __restrict__ H3) {
    __shared__ float hs[8 * 64];
    __shared__ float ws[64 * 40];
    const int r0 = blockIdx.x * 8;

    for (int i = threadIdx.x; i < 8 * 64; i += 320) {
        int r = r0 + (i >> 6);
        hs[i] = (r < N_NODES) ? H2[(long)r * 64 + (i & 63)] : 0.f;
    }
    for (int i = threadIdx.x; i < 64 * 40; i += 320) ws[i] = W2[i];
    __syncthreads();

    const int rl = threadIdx.x / 40;
    const int d = threadIdx.x % 40;
    float acc = 0.f;
    #pragma unroll
    for (int k = 0; k < 64; ++k) acc += hs[rl * 64 + k] * ws[k * 40 + d];

    const int r = r0 + rl;
    if (r < N_NODES) H3[(long)r * 40 + d] = f2bf(acc);
}

extern "C" void kernel_launch(void* const* d_in, const int* in_sizes, int n_in,
                              void* d_out, int out_size, void* d_ws, size_t ws_size,
                              hipStream_t stream) {
    const float* x       = (const float*)d_in[0];
    const float* W1      = (const float*)d_in[1];
    const float* W2      = (const float*)d_in[2];
    const float* adj_val = (const float*)d_in[3];
    const int*   adj_row = (const int*)d_in[4];
    const int*   adj_col = (const int*)d_in[5];
    float* out = (float*)d_out;

    char* ws = (char*)d_ws;
    const size_t OFF_H1     = 0;            // bf16 h1: 12.8 MB (h3 bf16 8 MB overlays)
    const size_t OFF_H2     = 12800000;     // fp32 h2: 25.6 MB
    const size_t OFF_EDGES  = 38400000;     // int2 edges: 25.6 MB
    const size_t OFF_RANK   = 64000000;     // int rank: 12.8 MB
    const size_t OFF_ROWPTR = 76800000;     // 400,004 B
    const size_t OFF_DEG    = 77200016;     // 400,000 B
    const size_t OFF_PART   = 77600016;     // 2,048 B
    const size_t OFF_W1F    = 77602064;     // bf16 frag-ordered W1: 65,536 B (16B-aligned)

    ushort* h1     = (ushort*)(ws + OFF_H1);
    float*  h2     = (float*)(ws + OFF_H2);
    ushort* h3     = (ushort*)(ws + OFF_H1);
    int2*   edges  = (int2*)(ws + OFF_EDGES);
    int*    rank   = (int*)(ws + OFF_RANK);
    int*    rowptr = (int*)(ws + OFF_ROWPTR);
    int*    deg    = (int*)(ws + OFF_DEG);
    int*    part   = (int*)(ws + OFF_PART);
    ushort* w1f    = (ushort*)(ws + OFF_W1F);

    // W1 -> bf16 fragment order (tiny, once per call)
    w1cvt_kernel<<<128, 256, 0, stream>>>(W1, w1f);

    // gemm1 (MFMA): stream x before CSR build so CSR set stays L3-resident
    gemm1_mfma_kernel<<<(N_NODES + 63) / 64, 256, 0, stream>>>(x, w1f, h1);

    // ---- CSR build (atomic-free scatter) ----
    zero_int_kernel<<<SCAN_NB, 256, 0, stream>>>(deg, N_NODES);
    hist_kernel<<<(N_EDGES / 8 + 255) / 256, 256, 0, stream>>>(adj_row, deg, rank);
    scan_a_kernel<<<SCAN_NB, 256, 0, stream>>>(deg, rowptr, part);
    scan_b_kernel<<<1, 512, 0, stream>>>(part, rowptr);
    scan_c_kernel<<<SCAN_NB, 256, 0, stream>>>(rowptr, part);
    scatter_kernel<<<(N_EDGES / 8 + 255) / 256, 256, 0, stream>>>(adj_row, adj_col, adj_val,
                                                                  rowptr, rank, edges);

    // ---- sparse pipeline ----
    spmm_csr_kernel<64, true><<<(N_NODES + 3) / 4, 256, 0, stream>>>(rowptr, edges, h1, h2);
    gemm2_kernel<<<(N_NODES + 7) / 8, 320, 0, stream>>>(h2, W2, h3);
    spmm_csr_kernel<40, false><<<(N_NODES + 3) / 4, 256, 0, stream>>>(rowptr, edges, h3, out);
}